// Round 7
// baseline (638.305 us; speedup 1.0000x reference)
//
#include <hip/hip_runtime.h>
#include <hip/hip_bf16.h>
#include <math.h>

#define N_NODES 65536
#define NDIR 9
#define NEDGE 589824
#define NBINS (N_NODES*NDIR)        // bin = dst*9 + sel (contiguous per node)
#define TILE_M 32
#define SKEY_CAP 512

typedef __attribute__((ext_vector_type(8))) short short8;
typedef __attribute__((ext_vector_type(4))) float f32x4;

__device__ inline float bf2f(unsigned short u){ return __uint_as_float(((unsigned int)u)<<16); }
__device__ inline unsigned short f2bf(float f){
  unsigned int x = __float_as_uint(f);
  x += 0x7fff + ((x>>16)&1);           // round-to-nearest-even
  return (unsigned short)(x>>16);
}
__device__ inline float elu1(float x){ return x>0.f ? x : expm1f(x); }

// ---- fused prep: fold BN into W (bf16, [n][k]), biases, zero hist, cast x ----
// Wt1 rows 0..1151 = conv1 dirs, rows 1152..1279 = W3*s3. Wt2 = conv2 dirs.
__global__ void prep_all(const float* __restrict__ x,
                         const float* __restrict__ W1, const float* __restrict__ W2,
                         const float* __restrict__ W3,
                         const float* __restrict__ b1, const float* __restrict__ g1,
                         const float* __restrict__ be1, const float* __restrict__ rm1, const float* __restrict__ rv1,
                         const float* __restrict__ b2, const float* __restrict__ g2,
                         const float* __restrict__ be2, const float* __restrict__ rm2, const float* __restrict__ rv2,
                         const float* __restrict__ b3, const float* __restrict__ g3,
                         const float* __restrict__ be3, const float* __restrict__ rm3, const float* __restrict__ rv3,
                         unsigned short* __restrict__ Wt1, unsigned short* __restrict__ Wt2,
                         float* __restrict__ bias1, float* __restrict__ bias2,
                         float* __restrict__ bias3, float* __restrict__ s3v,
                         int* __restrict__ hist, unsigned short* __restrict__ xb){
  int idx = blockIdx.x*256 + threadIdx.x;
  const float eps = 1e-5f;
  if (idx < 163840) {                              // Wt1
    int n = idx >> 7, k = idx & 127;
    float v;
    if (n < 1152) { int d = n >> 7, c = n & 127;
      float s = g1[c]*rsqrtf(rv1[c]+eps); v = W1[(d*128 + k)*128 + c] * s; }
    else { int c = n - 1152;
      float s = g3[c]*rsqrtf(rv3[c]+eps); v = W3[k*128 + c] * s; }
    Wt1[idx] = f2bf(v);
  } else if (idx < 311296) {                       // Wt2
    int j = idx - 163840;
    int n = j >> 7, k = j & 127;
    int d = n >> 7, c = n & 127;
    float s = g2[c]*rsqrtf(rv2[c]+eps);
    Wt2[j] = f2bf(W2[(d*128 + k)*128 + c] * s);
  } else if (idx < 311424) {                       // biases
    int c = idx - 311296;
    float s1 = g1[c]*rsqrtf(rv1[c]+eps);
    bias1[c] = (b1[c]-rm1[c])*s1 + be1[c];
    float s2 = g2[c]*rsqrtf(rv2[c]+eps);
    bias2[c] = (b2[c]-rm2[c])*s2 + be2[c];
    float s3 = g3[c]*rsqrtf(rv3[c]+eps);
    bias3[c] = (b3[c]-rm3[c])*s3 + be3[c];
    s3v[c] = s3;
  } else if (idx < 311424 + NBINS) {               // zero hist
    hist[idx - 311424] = 0;
  } else {                                         // xcast: 8 floats/thread
    int j = idx - (311424 + NBINS);
    if (j < N_NODES*16) {
      int i = j*8;
      f32x4 f0 = *(const f32x4*)(x + i);
      f32x4 f1 = *(const f32x4*)(x + i + 4);
      short8 t;
      #pragma unroll
      for (int jj = 0; jj < 4; jj++){ t[jj] = (short)f2bf(f0[jj]); t[4+jj] = (short)f2bf(f1[jj]); }
      *(short8*)(xb + i) = t;
    }
  }
}

// ---- CSR build over (dst,sel) bins, bin = dst*9+sel ----
__global__ void hist_k(const int* __restrict__ dst, const int* __restrict__ sel,
                       int* __restrict__ hist){
  int e = blockIdx.x*256 + threadIdx.x;
  atomicAdd(&hist[dst[e]*9 + sel[e]], 1);
}

// exclusive scan of 1024 ints per block; block total -> bsum[blockIdx]
__global__ void scan1_k(const int* __restrict__ in, int* __restrict__ out, int* __restrict__ bsum){
  __shared__ int wsum[4];
  int t = threadIdx.x;
  int base = blockIdx.x*1024 + t*4;
  int4 v = *(const int4*)(in + base);
  int s = v.x + v.y + v.z + v.w;
  int lane = t & 63, w = t >> 6;
  int inc = s;
  #pragma unroll
  for (int o = 1; o < 64; o <<= 1){ int n = __shfl_up(inc, o); if (lane >= o) inc += n; }
  if (lane == 63) wsum[w] = inc;
  __syncthreads();
  int acc = 0;
  for (int i = 0; i < w; i++) acc += wsum[i];
  int ex = acc + inc - s;
  out[base] = ex; out[base+1] = ex + v.x; out[base+2] = ex + v.x + v.y; out[base+3] = ex + v.x + v.y + v.z;
  if (t == 255) bsum[blockIdx.x] = acc + inc;
}

__global__ void scan3_k(int* __restrict__ rs, const int* __restrict__ bsumx, int* __restrict__ cursor){
  int i = blockIdx.x*256 + threadIdx.x;
  int v = rs[i] + bsumx[i >> 10];
  rs[i] = v; cursor[i] = v;
  if (i == 0) rs[NBINS] = NEDGE;        // sentinel: end(bin b) == rs[b+1]
}

__global__ void scatter_k(const int* __restrict__ src, const int* __restrict__ dst,
                          const int* __restrict__ sel,
                          int* __restrict__ cursor, int* __restrict__ sorted){
  int e = blockIdx.x*256 + threadIdx.x;
  int bin = dst[e]*9 + sel[e];
  int pos = atomicAdd(&cursor[bin], 1);
  sorted[pos] = src[e];
}

// ---- MFMA: wave computes all 32 rows x 32 cols (cols [w*32,w*32+32)) ----
__device__ __forceinline__ void mfma_tile(f32x4 acc[2][2],
                                          const unsigned short* agg,
                                          const unsigned short* __restrict__ Wd,
                                          int w, int q, int r){
  #pragma unroll
  for (int kk = 0; kk < 4; kk++){
    const unsigned short* wp = Wd + (size_t)(w*32 + r)*128 + kk*32 + q*8;
    short8 b0 = *(const short8*)wp;
    short8 b1 = *(const short8*)(wp + 16*128);
    #pragma unroll
    for (int mt = 0; mt < 2; mt++){
      short8 av = *(const short8*)&agg[(mt*16 + r)*136 + kk*32 + q*8];
      acc[mt][0] = __builtin_amdgcn_mfma_f32_16x16x32_bf16(av, b0, acc[mt][0], 0, 0, 0);
      acc[mt][1] = __builtin_amdgcn_mfma_f32_16x16x32_bf16(av, b1, acc[mt][1], 0, 0, 0);
    }
  }
}

// ---- fused layer: per 32-node block, per dir: 4-chain gather -> LDS, MFMA @ W_d.
// Each thread: 4 bins (rows g8+8t), 8B/lane loads, merged max-count loop ->
// 4 independent global loads in flight (R6 had ~1: latency-bound).
// L2: 10th phase gathers X on sel==0 bins; residual add done by MFMA C-operand.
template<int IS_L2>
__global__ __launch_bounds__(256, 8) void layer_k(
    const unsigned short* __restrict__ H,     // layer input activations [N][128] bf16
    const unsigned short* __restrict__ X,     // xb (shortcut input, L2 only)
    const unsigned short* __restrict__ Wf,    // [1152][128] folded dir weights
    const unsigned short* __restrict__ W3f,   // [128][128] folded shortcut weights (L2)
    const int* __restrict__ rs, const int* __restrict__ sorted,
    const float* __restrict__ biasA, const float* __restrict__ bias3,
    const float* __restrict__ s3v,
    unsigned short* __restrict__ outB, float* __restrict__ outF){
  __shared__ __align__(16) unsigned short agg[TILE_M*136];   // 8.7 KB
  __shared__ int skey[SKEY_CAP];                              // 2 KB
  __shared__ int rsl[TILE_M*9 + 1];                           // 1.2 KB
  const int tid = threadIdx.x;
  const int w = tid >> 6, lane = tid & 63;
  const int q = lane >> 4, r = lane & 15;
  const int g8 = tid >> 5, c8 = tid & 31;                     // 32 lanes/row, 8B chunk
  const int m0 = blockIdx.x * TILE_M;

  for (int i = tid; i <= TILE_M*9; i += 256) rsl[i] = rs[m0*9 + i];
  __syncthreads();
  const int lo = rsl[0];
  const int cnt = rsl[TILE_M*9] - lo;
  for (int i = tid; i < cnt && i < SKEY_CAP; i += 256) skey[i] = sorted[lo + i];

  f32x4 acc[2][2];
  #pragma unroll
  for (int mt = 0; mt < 2; mt++){ acc[mt][0] = (f32x4){0,0,0,0}; acc[mt][1] = (f32x4){0,0,0,0}; }

  const int NPH = IS_L2 ? 10 : 9;
  #pragma unroll 1
  for (int d = 0; d < NPH; d++){
    const bool scph = IS_L2 && (d == 9);
    const unsigned short* T = scph ? X : H;
    const int dd = scph ? 0 : d;
    __syncthreads();                     // skey ready (d=0) / agg consumed (d>0)

    int s[4], e[4];
    #pragma unroll
    for (int t = 0; t < 4; t++){
      int b = (g8 + 8*t)*9 + dd;
      s[t] = rsl[b] - lo; e[t] = rsl[b+1] - lo;
    }
    f32x4 A[4];
    #pragma unroll
    for (int t = 0; t < 4; t++) A[t] = (f32x4){0,0,0,0};
    int n = max(max(e[0]-s[0], e[1]-s[1]), max(e[2]-s[2], e[3]-s[3]));
    for (int k = 0; k < n; k++){
      #pragma unroll
      for (int t = 0; t < 4; t++){
        int i = s[t] + k;
        if (i < e[t]){
          int key = (i < SKEY_CAP) ? skey[i] : sorted[lo + i];
          uint2 v = *(const uint2*)(T + (size_t)key*128 + c8*4);
          A[t][0] += bf2f((unsigned short)(v.x & 0xffff));
          A[t][1] += bf2f((unsigned short)(v.x >> 16));
          A[t][2] += bf2f((unsigned short)(v.y & 0xffff));
          A[t][3] += bf2f((unsigned short)(v.y >> 16));
        }
      }
    }
    #pragma unroll
    for (int t = 0; t < 4; t++){
      unsigned int p0 = (unsigned int)f2bf(A[t][0]) | ((unsigned int)f2bf(A[t][1]) << 16);
      unsigned int p1 = (unsigned int)f2bf(A[t][2]) | ((unsigned int)f2bf(A[t][3]) << 16);
      uint2 o = {p0, p1};
      *(uint2*)(agg + (size_t)(g8 + 8*t)*136 + c8*4) = o;
    }
    __syncthreads();

    if (scph){
      // acc currently = conv2 pre-activation; fold BN2/ELU/BN3-scale in place,
      // then let the shortcut MFMA do "+ sc" via its C operand.
      #pragma unroll
      for (int mt = 0; mt < 2; mt++)
        #pragma unroll
        for (int n2 = 0; n2 < 2; n2++){
          int col = w*32 + n2*16 + r;
          float bA = biasA[col], b3 = bias3[col], s3 = s3v[col];
          #pragma unroll
          for (int rr = 0; rr < 4; rr++)
            acc[mt][n2][rr] = elu1(acc[mt][n2][rr] + bA)*s3 + b3;
        }
      mfma_tile(acc, agg, W3f, w, q, r);
    } else {
      mfma_tile(acc, agg, Wf + (size_t)dd*128*128, w, q, r);
    }
  }

  if constexpr (!IS_L2){
    #pragma unroll
    for (int mt = 0; mt < 2; mt++)
      #pragma unroll
      for (int n2 = 0; n2 < 2; n2++){
        int col = w*32 + n2*16 + r;
        float bA = biasA[col];
        #pragma unroll
        for (int rr = 0; rr < 4; rr++){
          int row = m0 + mt*16 + q*4 + rr;
          outB[(size_t)row*128 + col] = f2bf(elu1(acc[mt][n2][rr] + bA));
        }
      }
  } else {
    #pragma unroll
    for (int mt = 0; mt < 2; mt++)
      #pragma unroll
      for (int n2 = 0; n2 < 2; n2++){
        int col = w*32 + n2*16 + r;
        #pragma unroll
        for (int rr = 0; rr < 4; rr++){
          int row = m0 + mt*16 + q*4 + rr;
          outF[(size_t)row*128 + col] = elu1(acc[mt][n2][rr]);
        }
      }
  }
}

extern "C" void kernel_launch(void* const* d_in, const int* in_sizes, int n_in,
                              void* d_out, int out_size, void* d_ws, size_t ws_size,
                              hipStream_t stream){
  const float* x   = (const float*)d_in[0];
  const int*   ei  = (const int*)d_in[1];
  const int*   sel = (const int*)d_in[2];
  const float* W1  = (const float*)d_in[3];
  const float* b1  = (const float*)d_in[4];
  const float* g1  = (const float*)d_in[5];
  const float* be1 = (const float*)d_in[6];
  const float* rm1 = (const float*)d_in[7];
  const float* rv1 = (const float*)d_in[8];
  const float* W2  = (const float*)d_in[9];
  const float* b2  = (const float*)d_in[10];
  const float* g2  = (const float*)d_in[11];
  const float* be2 = (const float*)d_in[12];
  const float* rm2 = (const float*)d_in[13];
  const float* rv2 = (const float*)d_in[14];
  const float* W3  = (const float*)d_in[15];
  const float* b3  = (const float*)d_in[16];
  const float* g3  = (const float*)d_in[17];
  const float* be3 = (const float*)d_in[18];
  const float* rm3 = (const float*)d_in[19];
  const float* rv3 = (const float*)d_in[20];

  char* ws = (char*)d_ws;
  unsigned short* xb   = (unsigned short*)(ws);                  // 16.78 MB
  unsigned short* h1   = (unsigned short*)(ws + 16777216);       // 16.78 MB
  unsigned short* Wt1  = (unsigned short*)(ws + 33554432);       // 327,680 B (incl. W3fold @ rows 1152+)
  unsigned short* Wt2  = (unsigned short*)(ws + 33882112);       // 294,912 B
  float* bias1  = (float*)(ws + 34177024);
  float* bias2  = bias1 + 128;
  float* bias3  = bias1 + 256;
  float* s3v    = bias1 + 384;
  int* hist     = (int*)(ws + 34179072);                         // NBINS*4 = 2.36 MB
  int* rs       = (int*)(ws + 36538368);                         // (NBINS+1)*4
  int* cursor   = (int*)(ws + 38897920);                         // NBINS*4
  int* bsum     = (int*)(ws + 41257216);                         // 4 KB
  int* bsumx    = (int*)(ws + 41261312);                         // 4 KB
  int* bsumT    = (int*)(ws + 41265408);                         // 16 B
  int* sorted   = (int*)(ws + 41265664);                         // NEDGE*4; end ~43.6 MB

  const int* srcp = ei;
  const int* dstp = ei + NEDGE;

  // threads: 163840 Wt1 + 147456 Wt2 + 128 bias + 589824 hist-zero + 1048576 xcast
  prep_all<<<(163840+147456+128+NBINS+N_NODES*16+255)/256, 256, 0, stream>>>(
      x, W1, W2, W3, b1,g1,be1,rm1,rv1, b2,g2,be2,rm2,rv2, b3,g3,be3,rm3,rv3,
      Wt1, Wt2, bias1, bias2, bias3, s3v, hist, xb);
  hist_k<<<NEDGE/256, 256, 0, stream>>>(dstp, sel, hist);
  scan1_k<<<NBINS/1024, 256, 0, stream>>>(hist, rs, bsum);       // 576 blocks
  scan1_k<<<1, 256, 0, stream>>>(bsum, bsumx, bsumT);            // scan 576 block sums (tail garbage unused)
  scan3_k<<<NBINS/256, 256, 0, stream>>>(rs, bsumx, cursor);
  scatter_k<<<NEDGE/256, 256, 0, stream>>>(srcp, dstp, sel, cursor, sorted);

  layer_k<0><<<2048, 256, 0, stream>>>(xb, nullptr, Wt1, nullptr, rs, sorted,
                                       bias1, nullptr, nullptr, h1, nullptr);
  layer_k<1><<<2048, 256, 0, stream>>>(h1, xb, Wt2, Wt1 + 1152*128, rs, sorted,
                                       bias2, bias3, s3v, nullptr, (float*)d_out);
}